// Round 3
// baseline (267.594 us; speedup 1.0000x reference)
//
#include <hip/hip_runtime.h>
#include <stdint.h>
#include <limits.h>

// Problem constants (reference: B=4, N=8192, C=64, OUT=64, KNN=36)
#define BB 4
#define NN 8192
#define CC 64
#define OUTD 64
#define KK 36
#define NPTS (BB * NN)          // 32768
#define NBIN 129                // bins 0..128 (0 and 128 are clamp catch-alls)
// t = signed(float_bits(d2)) >> 20 (arith); bin = med3_i32(t,960,1088) - 960.
// Negative d2 (fp rounding) -> t very negative -> bin 0. One integer t per bin.
//
// xyzw layout: PAIR-INTERLEAVED. For even j: 8 floats
//   [x_j, x_j1, y_j, y_j1, z_j, z_j1, w_j, w_j1]   (j1 = j+1; 32 B per pair)
//
// R3 fetch path: per-wave LDS staging ring (global_load_lds, vmcnt, coalesced
// 16B/lane) + wave-uniform broadcast ds_read_b128 consumption (in-order DS
// FIFO -> counted lgkm waits coexist with the ds_add histogram atomics).
// This replaces SMEM s_load, whose out-of-order returns force lgkmcnt(0)
// drains of the atomic queue and whose latency can't be covered by the
// SGPR-capped (2-set) ping-pong (R2 evidence: 65% VALUBusy plateau).

typedef float v2f __attribute__((ext_vector_type(2)));

static __device__ __forceinline__ int laneid() { return threadIdx.x & 63; }
static __device__ __forceinline__ int waveid_uniform() {
    return __builtin_amdgcn_readfirstlane((int)(threadIdx.x >> 6));
}
static __device__ __forceinline__ float rdlane_f(float v, int l) {
    return __int_as_float(__builtin_amdgcn_readlane(__float_as_int(v), l));
}
static __device__ __forceinline__ unsigned long long shflx_ull(
        unsigned long long v, int m) {
    uint32_t lo = (uint32_t)v, hi = (uint32_t)(v >> 32);
    lo = (uint32_t)__shfl_xor((int)lo, m, 64);
    hi = (uint32_t)__shfl_xor((int)hi, m, 64);
    return ((unsigned long long)hi << 32) | lo;
}
// DPP helper: VALU-pipe cross-lane (no LDS). ctrl/bound must be constants.
#define DPP_F(oldv, v, ctrl, bound) \
    __int_as_float(__builtin_amdgcn_update_dpp( \
        __float_as_int(oldv), __float_as_int(v), (ctrl), 0xf, 0xf, (bound)))
#define DPP_U(v, ctrl) \
    (uint32_t)__builtin_amdgcn_update_dpp(0, (int)(v), (ctrl), 0xf, 0xf, true)

// 64-lane sum: result in lane 63 (row_shr prefix + row_bcast combine)
static __device__ __forceinline__ float wave_sum_dpp(float v) {
    v += DPP_F(0.0f, v, 0x111, true);   // row_shr:1
    v += DPP_F(0.0f, v, 0x112, true);   // row_shr:2
    v += DPP_F(0.0f, v, 0x114, true);   // row_shr:4
    v += DPP_F(0.0f, v, 0x118, true);   // row_shr:8
    v += DPP_F(0.0f, v, 0x142, true);   // row_bcast:15
    v += DPP_F(0.0f, v, 0x143, true);   // row_bcast:31
    return rdlane_f(v, 63);
}
// 64-lane max: OOB lanes keep old=v (no-op under max)
static __device__ __forceinline__ float wave_max_dpp(float v) {
    v = fmaxf(v, DPP_F(v, v, 0x111, false));
    v = fmaxf(v, DPP_F(v, v, 0x112, false));
    v = fmaxf(v, DPP_F(v, v, 0x114, false));
    v = fmaxf(v, DPP_F(v, v, 0x118, false));
    v = fmaxf(v, DPP_F(v, v, 0x142, false));
    v = fmaxf(v, DPP_F(v, v, 0x143, false));
    return rdlane_f(v, 63);
}
// 64-lane inclusive prefix sum (u32), per-lane result
static __device__ __forceinline__ uint32_t prefix_incl_u32(uint32_t v) {
    v += DPP_U(v, 0x111);
    v += DPP_U(v, 0x112);
    v += DPP_U(v, 0x114);
    v += DPP_U(v, 0x118);
    v += DPP_U(v, 0x142);
    v += DPP_U(v, 0x143);
    return v;
}
static __device__ __forceinline__ uint32_t rdlane_u(uint32_t v, int l) {
    return (uint32_t)__builtin_amdgcn_readlane((int)v, l);
}

// async global->LDS: 16 B per lane, dest = lds_base + lane*16 (HW rule)
static __device__ __forceinline__ void stage16(float* lds, const float* g) {
    __builtin_amdgcn_global_load_lds(
        (const __attribute__((address_space(1))) void*)g,
        (__attribute__((address_space(3))) void*)lds, 16, 0, 0);
}
#define WAITVM(N) do { \
        asm volatile("s_waitcnt vmcnt(" #N ")" ::: "memory"); \
        __builtin_amdgcn_sched_barrier(0); } while (0)

// ---------------------------------------------------------------------------
// Kernel 1: v_feat = relu([feature, xyz] @ W_v + b_v)  + pair-interleaved xyzw.
// One wave handles 8 points. Block = 256 = 4 waves. grid = NPTS/32.
// ---------------------------------------------------------------------------
__global__ __launch_bounds__(256) void k_vfeat(
    const float* __restrict__ feat, const float* __restrict__ xyz,
    const float* __restrict__ Wv, const float* __restrict__ bv,
    float* __restrict__ vfeat, float* __restrict__ xp)   // xp: interleaved xyzw
{
    __shared__ float fb[4][8][64];
    __shared__ float xb[4][8][3];
    const int lane = laneid();
    const int wv = waveid_uniform();
    const int pbase = blockIdx.x * 32 + wv * 8;

    #pragma unroll
    for (int pp = 0; pp < 8; ++pp)
        fb[wv][pp][lane] = feat[(pbase + pp) * CC + lane];
    if (lane < 24)
        xb[wv][lane / 3][lane % 3] = xyz[pbase * 3 + lane];
    // same-wave LDS write->read: in-order per wave, compiler inserts lgkmcnt

    const float b0 = bv[lane];
    float acc[8];
    #pragma unroll
    for (int pp = 0; pp < 8; ++pp) acc[pp] = b0;

    #pragma unroll 4
    for (int c = 0; c < CC; ++c) {
        float w = Wv[c * OUTD + lane];
        #pragma unroll
        for (int pp = 0; pp < 8; ++pp)
            acc[pp] = fmaf(fb[wv][pp][c], w, acc[pp]);
    }
    const float wx = Wv[64 * OUTD + lane];
    const float wy = Wv[65 * OUTD + lane];
    const float wz = Wv[66 * OUTD + lane];
    #pragma unroll
    for (int pp = 0; pp < 8; ++pp) {
        float a = acc[pp];
        a = fmaf(xb[wv][pp][0], wx, a);
        a = fmaf(xb[wv][pp][1], wy, a);
        a = fmaf(xb[wv][pp][2], wz, a);
        vfeat[(pbase + pp) * OUTD + lane] = fmaxf(a, 0.0f);
    }
    if (lane < 8) {
        const int p = pbase + lane;
        const float x = xb[wv][lane][0], y = xb[wv][lane][1], z = xb[wv][lane][2];
        const float sq = (x * x + y * y) + z * z;
        const int base = (p >> 1) * 8 + (p & 1);    // pair-interleaved slot
        xp[base + 0] = x;
        xp[base + 2] = y;
        xp[base + 4] = z;
        xp[base + 6] = sq;
    }
}

// ---------------------------------------------------------------------------
// Kernel 2: 36-NN via per-query float-bit histogram selection.
// 512 blocks x 1024 thr, 64 queries/block (lane-per-query), 2 blocks/CU.
//
// Fetch: per-wave ring of 2 x 1KB LDS slots. STAGE = one global_load_lds
// (64 lanes x 16 B, coalesced, vmcnt). Consume = broadcast ds_read_b128.
// Main loops contain NO other vmem ops (pass-2 direct-emits go to LDS
// dirbuf, flushed at the end) so vmcnt(1)/(0) literals are exact.
//
// Pass 2 thresholds in BITS domain (validated on HW in R1/R2):
//   bin <= Bq  <=>  bits <= ((960+Bq+1)<<20)-1 ;  direct <=> bits < (960+Bq)<<20
//   exact key  max(bits,0)  ==  float_bits(fmaxf(d2,0)).
// Tie-break matches lax.top_k: (distance-bits, then smaller index).
// ---------------------------------------------------------------------------
__global__ __launch_bounds__(1024, 8) void k_knn(
    const float* __restrict__ xpAll, int* __restrict__ idx_ws)
{
    __shared__ __align__(16) uint32_t hist[NBIN * 64];   // 33.0 KB; buf overlay in p2
    __shared__ __align__(16) float stage[16][2][256];    // 32.0 KB ring (1KB/slot)
    __shared__ int dirbuf[64][36];                       // 9.0 KB direct emits
    __shared__ int binB[64];
    __shared__ int cumLoA[64];
    __shared__ uint32_t bufCnt[64];
    __shared__ uint32_t dirCnt[64];

    const int lane = laneid();
    const int wv = waveid_uniform();               // 0..15
    const int batch = blockIdx.x >> 7;             // 128 blocks per batch
    const int qbase = (blockIdx.x & 127) << 6;
    const int q = qbase + lane;                    // local query id 0..8191
    const float* __restrict__ xp = xpAll + (size_t)batch * NN * 4;

    // per-lane query fetch from the interleaved layout (once per block)
    const int pr = q >> 1, sub0 = q & 1;
    const float Qx = xp[pr * 8 + sub0 + 0];
    const float Qy = xp[pr * 8 + sub0 + 2];
    const float Qz = xp[pr * 8 + sub0 + 4];
    const float Qw = xp[pr * 8 + sub0 + 6];
    const v2f qx = { Qx, Qx };
    const v2f qy = { Qy, Qy };
    const v2f qz = { Qz, Qz };
    const v2f qw = { Qw, Qw };
    const v2f m2 = { -2.0f, -2.0f };

    const int laneAdj = lane - 960 * 64;           // fold bin rebase into addressing
    const float* __restrict__ xpw = xp + wv * 2048;   // wave chunk (8 KB)
    const int lane4 = lane * 4;                    // 16 B per lane within a slot

    for (int i = threadIdx.x; i < NBIN * 64; i += 1024) hist[i] = 0u;
    if (threadIdx.x < 64) { bufCnt[threadIdx.x] = 0u; dirCnt[threadIdx.x] = 0u; }
    __syncthreads();   // also drains vmcnt -> only stages outstanding after this

#define STAGE(slot, sub) stage16(&stage[wv][slot][0], xpw + (sub) * 256 + lane4)

// distance math for one 2-pair group (4 candidates); identical op sequence in
// both passes -> identical bits -> histogram/selection consistency
#define GDIST(Sp, g) \
        float4 _A = (Sp)[4 * (g) + 0], _B = (Sp)[4 * (g) + 1]; \
        float4 _C = (Sp)[4 * (g) + 2], _D = (Sp)[4 * (g) + 3]; \
        v2f cx0 = { _A.x, _A.y }, cy0 = { _A.z, _A.w }; \
        v2f cz0 = { _B.x, _B.y }, cw0 = { _B.z, _B.w }; \
        v2f cx1 = { _C.x, _C.y }, cy1 = { _C.z, _C.w }; \
        v2f cz1 = { _D.x, _D.y }, cw1 = { _D.z, _D.w }; \
        v2f dot0 = __builtin_elementwise_fma(qx, cx0, \
                   __builtin_elementwise_fma(qy, cy0, qz * cz0)); \
        v2f d20  = __builtin_elementwise_fma(m2, dot0, qw + cw0); \
        v2f dot1 = __builtin_elementwise_fma(qx, cx1, \
                   __builtin_elementwise_fma(qy, cy1, qz * cz1)); \
        v2f d21  = __builtin_elementwise_fma(m2, dot1, qw + cw1);

#define CONS1(slot) do { \
        const float4* Sp = (const float4*)&stage[wv][slot][0]; \
        _Pragma("unroll") \
        for (int g = 0; g < 16; ++g) { \
            GDIST(Sp, g) \
            int t0 = ((int)__float_as_uint(d20.x)) >> 20; \
            int t1 = ((int)__float_as_uint(d20.y)) >> 20; \
            int t2 = ((int)__float_as_uint(d21.x)) >> 20; \
            int t3 = ((int)__float_as_uint(d21.y)) >> 20; \
            int b0 = min(max(t0, 960), 1088);            /* v_med3_i32 */ \
            int b1 = min(max(t1, 960), 1088); \
            int b2 = min(max(t2, 960), 1088); \
            int b3 = min(max(t3, 960), 1088); \
            atomicAdd(&hist[b0 * 64 + laneAdj], 1u); \
            atomicAdd(&hist[b1 * 64 + laneAdj], 1u); \
            atomicAdd(&hist[b2 * 64 + laneAdj], 1u); \
            atomicAdd(&hist[b3 * 64 + laneAdj], 1u); \
        } } while (0)

    // ---- pass 1: histogram; 2-slot ring, vmcnt-counted waits ----
    {
        STAGE(0, 0); STAGE(1, 1);
        #pragma unroll 1
        for (int sub = 0; sub < 6; ++sub) {
            const int s = sub & 1;
            WAITVM(1);
            CONS1(s);
            STAGE(s, sub + 2);
        }
        WAITVM(1); CONS1(0);
        WAITVM(0); CONS1(1);
    }
    __syncthreads();

    // ---- crossing bin: wave-parallel (wave wv owns queries 4wv..4wv+3) ----
    // hist[b*64+t] reads are same-bank across lanes (stride 256B) - the few
    // conflicted reads are far cheaper than the old 1-wave serial 129-scan.
    #pragma unroll 1
    for (int sc = 0; sc < 4; ++sc) {
        const int t = 4 * wv + sc;
        uint32_t c0 = hist[lane * 64 + t];
        uint32_t p0 = prefix_incl_u32(c0);
        unsigned long long m0 = __ballot((int)p0 >= KK);
        int Bq, cl;
        if (m0) {
            int l0 = __ffsll(m0) - 1;
            Bq = l0;
            cl = (int)(rdlane_u(p0, l0) - rdlane_u(c0, l0));
        } else {
            int s0 = (int)rdlane_u(p0, 63);
            uint32_t c1 = hist[(64 + lane) * 64 + t];
            uint32_t p1 = prefix_incl_u32(c1);
            unsigned long long m1 = __ballot(s0 + (int)p1 >= KK);
            if (m1) {
                int l1 = __ffsll(m1) - 1;
                Bq = 64 + l1;
                cl = s0 + (int)(rdlane_u(p1, l1) - rdlane_u(c1, l1));
            } else {
                Bq = 128;
                cl = s0 + (int)rdlane_u(p1, 63);
            }
        }
        if (lane == 0) { binB[t] = Bq; cumLoA[t] = cl; }
    }
    __syncthreads();

    // ---- per-lane BITS-domain thresholds for pass 2 ----
    const int Bq = binB[lane];
    const int TLb = (Bq > 0)    ? ((960 + Bq) << 20) : INT_MIN;
    const int THb = (Bq == 128) ? INT_MAX : (((960 + Bq + 1) << 20) - 1);
    const int gBase = batch * NN;

    // boundary buffer overlays dead hist: buf[query][pos], 64x64 ull = 32 KB
    unsigned long long* buf = (unsigned long long*)hist;

#define EMIT(Bx, jj) do { \
        if ((Bx) <= THb) {                       /* rare (~1% of candidates) */ \
            if ((Bx) < TLb) { \
                uint32_t pos = atomicAdd(&dirCnt[lane], 1u); \
                dirbuf[lane][(int)pos] = (jj);   /* pos < 36 by construction */ \
            } else { \
                uint32_t db = (uint32_t)max((Bx), 0);        /* exact key */ \
                uint32_t pos = atomicAdd(&bufCnt[lane], 1u); \
                if (pos < 64u) buf[lane * 64 + (int)pos] = \
                    ((unsigned long long)db << 32) | (uint32_t)(jj); \
            } \
        } } while (0)

#define CONS2(slot, sub) do { \
        const float4* Sp = (const float4*)&stage[wv][slot][0]; \
        const int jb = wv * 512 + (sub) * 64; \
        _Pragma("unroll") \
        for (int g = 0; g < 16; ++g) { \
            GDIST(Sp, g) \
            int B0 = (int)__float_as_uint(d20.x); \
            int B1 = (int)__float_as_uint(d20.y); \
            int B2 = (int)__float_as_uint(d21.x); \
            int B3 = (int)__float_as_uint(d21.y); \
            EMIT(B0, jb + 4 * g + 0); \
            EMIT(B1, jb + 4 * g + 1); \
            EMIT(B2, jb + 4 * g + 2); \
            EMIT(B3, jb + 4 * g + 3); \
        } } while (0)

    // ---- pass 2: one-compare hot path; same ring; zero global ops ----
    {
        STAGE(0, 0); STAGE(1, 1);
        #pragma unroll 1
        for (int sub = 0; sub < 6; ++sub) {
            const int s = sub & 1;
            WAITVM(1);
            CONS2(s, sub);
            STAGE(s, sub + 2);
        }
        WAITVM(1); CONS2(0, 6);
        WAITVM(0); CONS2(1, 7);
    }
    __syncthreads();

#undef STAGE
#undef GDIST
#undef CONS1
#undef CONS2
#undef EMIT

    // ---- final: flush direct entries; pick (36-cl) smallest boundary keys.
    // Parallel across all 16 waves: wave wv owns queries 4wv..4wv+3; keys
    // one-per-lane; each pick is a 6-step shfl_xor 64-bit min-reduce.
    #pragma unroll 1
    for (int sub = 0; sub < 4; ++sub) {
        const int t = 4 * wv + sub;                 // wave-uniform query slot
        const int cl = cumLoA[t];
        const int r = KK - cl;                      // >= 1 always
        const int M = min((int)bufCnt[t], 64);
        const int q2 = qbase + t;
        const int outp = (gBase + q2) * KK;
        if (lane < cl) idx_ws[outp + lane] = gBase + dirbuf[t][lane];
        unsigned long long key = (lane < M) ? buf[t * 64 + lane] : ~0ULL;
        #pragma unroll 1
        for (int i = 0; i < r; ++i) {
            unsigned long long mk = key;
            #pragma unroll
            for (int d = 32; d >= 1; d >>= 1) {
                unsigned long long o = shflx_ull(mk, d);
                mk = (o < mk) ? o : mk;
            }
            int jj = (mk == ~0ULL) ? q2 : (int)(uint32_t)(mk & 0xFFFFFFFFu);
            if (jj < 0 || jj >= NN) jj = q2;         // pathological fallback
            if (lane == 0) idx_ws[outp + cl + i] = gBase + jj;
            if (key == mk) key = ~0ULL;              // retire the winner
        }
    }
}

// ---------------------------------------------------------------------------
// Kernel 3: attention + projection (best-measured form). LDS only for
// G staging, two half-channel rounds G[4][36][33] (~19 KB -> 8 blocks/CU).
// F from SGPRs; softmax via DPP (VALU); weights/projection via v_readlane.
// grid = NPTS/4 blocks of 256, one point per wave. No __syncthreads.
// ---------------------------------------------------------------------------
#define IDX(k) ((((k) & 3) == 0 ? I[(k) >> 2].x : ((k) & 3) == 1 ? I[(k) >> 2].y : \
                 ((k) & 3) == 2 ? I[(k) >> 2].z : I[(k) >> 2].w) & (NPTS - 1))

__global__ __launch_bounds__(256) void k_att(
    const float* __restrict__ feat, const float* __restrict__ vfeat,
    const int* __restrict__ idxw, const float* __restrict__ Wsuf,
    const float* __restrict__ bsuf, float* __restrict__ out)
{
    __shared__ float G[4][KK][33];   // 19,008 B (stride 33 == 1 mod 32: <=2-way)
    const int lane = laneid();
    const int wv = waveid_uniform();
    const int p = blockIdx.x * 4 + wv;

    // preload all 36 neighbor indices (wave-uniform s_load)
    const int4* __restrict__ myidx4 = (const int4*)(idxw + p * KK);
    int4 I[9];
    #pragma unroll
    for (int t = 0; t < 9; ++t) I[t] = myidx4[t];

    const float* __restrict__ Fp = feat + (size_t)p * CC;  // uniform -> s_load

    const int half = lane >> 5;       // 0: rows 2kk, 1: rows 2kk+1
    const int cpart = lane & 31;      // column within the 32-wide half

    float a = 0.0f;
    #pragma unroll
    for (int h = 0; h < 2; ++h) {
        // stage half h: 18 wave-loads, each covering two rows' 32-col halves
        #pragma unroll
        for (int kk = 0; kk < 18; ++kk) {
            int jrow = half ? IDX(2 * kk + 1) : IDX(2 * kk);
            G[wv][2 * kk + half][cpart] = feat[(size_t)jrow * CC + h * 32 + cpart];
        }
        // partial logits over this channel half (lane = k < 36); F is scalar
        if (lane < KK) {
            #pragma unroll 8
            for (int c = 0; c < 32; ++c)
                a = fmaf(Fp[h * 32 + c], G[wv][lane][c], a);
        }
    }
    const float logit = (lane < KK) ? a : -1e30f;

    // softmax across the 36 logit lanes — DPP (VALU pipe), no LDS
    const float m = wave_max_dpp(logit);
    const float e = (lane < KK) ? __expf(logit - m) : 0.0f;
    const float s = wave_sum_dpp(e);
    const float w = e * __frcp_rn(s);            // per-lane weight (0 for >=36)

    // weighted V gather: lane = channel; weight broadcast via v_readlane
    float acc = 0.0f;
    #pragma unroll
    for (int k = 0; k < KK; ++k) {
        float wk = rdlane_f(w, k);
        int j = IDX(k);
        acc = fmaf(wk, vfeat[j * OUTD + lane], acc);
    }

    // projection: o[lane] = b[lane] + sum_c acc_c * Wsuf[c][lane]
    float o = bsuf[lane];
    #pragma unroll 8
    for (int c = 0; c < OUTD; ++c) {
        float ac = rdlane_f(acc, c);
        o = fmaf(ac, Wsuf[c * OUTD + lane], o);
    }
    out[(size_t)p * OUTD + lane] = o;

    if (p == 0 && lane == 0) out[(size_t)NPTS * OUTD] = (float)NN;  // scalar N
}

// ---------------------------------------------------------------------------
extern "C" void kernel_launch(void* const* d_in, const int* in_sizes, int n_in,
                              void* d_out, int out_size, void* d_ws, size_t ws_size,
                              hipStream_t stream)
{
    const float* feat = (const float*)d_in[0];
    const float* xyz  = (const float*)d_in[1];
    const float* Wv   = (const float*)d_in[2];
    const float* bv   = (const float*)d_in[3];
    const float* Wsuf = (const float*)d_in[4];
    const float* bsuf = (const float*)d_in[5];
    float* out = (float*)d_out;

    char* ws = (char*)d_ws;
    float* xp = (float*)ws;                                   // 512 KB interleaved
    float*  vfeat = (float*)(ws + (512 << 10));               // 8 MB
    int*    idxw  = (int*)(ws + (512 << 10) + (8 << 20));     // 4.5 MB

    k_vfeat<<<NPTS / 32, 256, 0, stream>>>(feat, xyz, Wv, bv, vfeat, xp);
    k_knn  <<<NPTS / 64, 1024, 0, stream>>>(xp, idxw);
    k_att  <<<NPTS / 4, 256, 0, stream>>>(feat, vfeat, idxw, Wsuf, bsuf, out);
}

// Round 6
// 244.216 us; speedup vs baseline: 1.0957x; 1.0957x over previous
//
#include <hip/hip_runtime.h>
#include <stdint.h>
#include <limits.h>

// Problem constants (reference: B=4, N=8192, C=64, OUT=64, KNN=36)
#define BB 4
#define NN 8192
#define CC 64
#define OUTD 64
#define KK 36
#define NPTS (BB * NN)          // 32768
#define NBIN 129                // bins 0..128 (0 and 128 are clamp catch-alls)
// t = signed(float_bits(d2)) >> 20 (arith); bin = med3_i32(t,960,1088) - 960.
// Negative d2 (fp rounding) -> t very negative -> bin 0. One integer t per bin.
//
// xyzw layout: PAIR-INTERLEAVED. For even j: 8 floats
//   [x_j, x_j1, y_j, y_j1, z_j, z_j1, w_j, w_j1]   (j1 = j+1; 32 B per pair)
//
// Ledger (HW-validated R0-R5):
//   R0/R2  SMEM s_load + pk math           -> fast (validated 135us k_knn)
//   R1     per-lane VMEM broadcast         -> 1.9x REGRESSION
//   R3     global_load_lds + ds_read       -> REGRESSION (DS pipe shared with
//          histogram atomics) + DPP prefix-scan row_mask bug (absmax 0.32)
//   R4/R5  4-buffer SGPR rotation          -> container died 2 rounds running
//          (4 attempts); no semantic fault found; QUARANTINED, unproven.
// This round: k_knn = byte-identical R2 (validated); the experiment is in
// k_att only (XCD-contiguous block swizzle for gather L2 locality).

typedef float v2f __attribute__((ext_vector_type(2)));

static __device__ __forceinline__ int laneid() { return threadIdx.x & 63; }
static __device__ __forceinline__ int waveid_uniform() {
    return __builtin_amdgcn_readfirstlane((int)(threadIdx.x >> 6));
}
static __device__ __forceinline__ float rdlane_f(float v, int l) {
    return __int_as_float(__builtin_amdgcn_readlane(__float_as_int(v), l));
}
static __device__ __forceinline__ unsigned long long shflx_ull(
        unsigned long long v, int m) {
    uint32_t lo = (uint32_t)v, hi = (uint32_t)(v >> 32);
    lo = (uint32_t)__shfl_xor((int)lo, m, 64);
    hi = (uint32_t)__shfl_xor((int)hi, m, 64);
    return ((unsigned long long)hi << 32) | lo;
}
// DPP helper: VALU-pipe cross-lane (no LDS). ctrl/bound must be constants.
#define DPP_F(oldv, v, ctrl, bound) \
    __int_as_float(__builtin_amdgcn_update_dpp( \
        __float_as_int(oldv), __float_as_int(v), (ctrl), 0xf, 0xf, (bound)))

// 64-lane sum: result in lane 63 (row_shr prefix + row_bcast combine).
// NOTE: lane-63 TOTAL is correct with full row_mask; intermediate lanes are
// NOT a valid prefix (R3 lesson - do not reuse this as a scan).
static __device__ __forceinline__ float wave_sum_dpp(float v) {
    v += DPP_F(0.0f, v, 0x111, true);   // row_shr:1
    v += DPP_F(0.0f, v, 0x112, true);   // row_shr:2
    v += DPP_F(0.0f, v, 0x114, true);   // row_shr:4
    v += DPP_F(0.0f, v, 0x118, true);   // row_shr:8
    v += DPP_F(0.0f, v, 0x142, true);   // row_bcast:15
    v += DPP_F(0.0f, v, 0x143, true);   // row_bcast:31
    return rdlane_f(v, 63);
}
// 64-lane max: OOB lanes keep old=v (no-op under max)
static __device__ __forceinline__ float wave_max_dpp(float v) {
    v = fmaxf(v, DPP_F(v, v, 0x111, false));
    v = fmaxf(v, DPP_F(v, v, 0x112, false));
    v = fmaxf(v, DPP_F(v, v, 0x114, false));
    v = fmaxf(v, DPP_F(v, v, 0x118, false));
    v = fmaxf(v, DPP_F(v, v, 0x142, false));
    v = fmaxf(v, DPP_F(v, v, 0x143, false));
    return rdlane_f(v, 63);
}

// ---------------------------------------------------------------------------
// Kernel 1: v_feat = relu([feature, xyz] @ W_v + b_v)  + pair-interleaved xyzw.
// One wave handles 8 points. Block = 256 = 4 waves. grid = NPTS/32.
// ---------------------------------------------------------------------------
__global__ __launch_bounds__(256) void k_vfeat(
    const float* __restrict__ feat, const float* __restrict__ xyz,
    const float* __restrict__ Wv, const float* __restrict__ bv,
    float* __restrict__ vfeat, float* __restrict__ xp)   // xp: interleaved xyzw
{
    __shared__ float fb[4][8][64];
    __shared__ float xb[4][8][3];
    const int lane = laneid();
    const int wv = waveid_uniform();
    const int pbase = blockIdx.x * 32 + wv * 8;

    #pragma unroll
    for (int pp = 0; pp < 8; ++pp)
        fb[wv][pp][lane] = feat[(pbase + pp) * CC + lane];
    if (lane < 24)
        xb[wv][lane / 3][lane % 3] = xyz[pbase * 3 + lane];
    // same-wave LDS write->read: in-order per wave, compiler inserts lgkmcnt

    const float b0 = bv[lane];
    float acc[8];
    #pragma unroll
    for (int pp = 0; pp < 8; ++pp) acc[pp] = b0;

    #pragma unroll 4
    for (int c = 0; c < CC; ++c) {
        float w = Wv[c * OUTD + lane];
        #pragma unroll
        for (int pp = 0; pp < 8; ++pp)
            acc[pp] = fmaf(fb[wv][pp][c], w, acc[pp]);
    }
    const float wx = Wv[64 * OUTD + lane];
    const float wy = Wv[65 * OUTD + lane];
    const float wz = Wv[66 * OUTD + lane];
    #pragma unroll
    for (int pp = 0; pp < 8; ++pp) {
        float a = acc[pp];
        a = fmaf(xb[wv][pp][0], wx, a);
        a = fmaf(xb[wv][pp][1], wy, a);
        a = fmaf(xb[wv][pp][2], wz, a);
        vfeat[(pbase + pp) * OUTD + lane] = fmaxf(a, 0.0f);
    }
    if (lane < 8) {
        const int p = pbase + lane;
        const float x = xb[wv][lane][0], y = xb[wv][lane][1], z = xb[wv][lane][2];
        const float sq = (x * x + y * y) + z * z;
        const int base = (p >> 1) * 8 + (p & 1);    // pair-interleaved slot
        xp[base + 0] = x;
        xp[base + 2] = y;
        xp[base + 4] = z;
        xp[base + 6] = sq;
    }
}

// ---------------------------------------------------------------------------
// Kernel 2: 36-NN via per-query float-bit histogram selection.
// 512 blocks x 1024 thr, 64 queries/block (lane-per-query), 2 blocks/CU.
// BYTE-IDENTICAL to the R2-validated version (135us, absmax 0.0):
//  (a) 2-buffer ping-pong of 4-pair candidate sets (2x s_load_dwordx16/set)
//  (b) final boundary-bin selection parallel across all 16 waves
//      (shfl_xor 64-bit min-reduce per pick); buf2[64][65] ull rows.
// Pass 2 thresholds in BITS domain:
//   bin <= Bq  <=>  bits <= ((960+Bq+1)<<20)-1 ;  direct <=> bits < (960+Bq)<<20
//   exact key  max(bits,0)  ==  float_bits(fmaxf(d2,0)).
// Tie-break matches lax.top_k: (distance-bits, then smaller index).
// ---------------------------------------------------------------------------
__global__ __launch_bounds__(1024, 8) void k_knn(
    const float* __restrict__ xpAll, int* __restrict__ idx_ws)
{
    __shared__ __align__(16) uint32_t hist[NBIN * 64];          // 33.0 KB
    __shared__ __align__(16) unsigned long long buf2[64][65];   // 33.3 KB
    __shared__ int binB[64];
    __shared__ int cumLoA[64];
    __shared__ uint32_t bufCnt[64];
    __shared__ uint32_t dirCnt[64];

    const int lane = laneid();
    const int wv = waveid_uniform();               // 0..15
    const int batch = blockIdx.x >> 7;             // 128 blocks per batch
    const int qbase = (blockIdx.x & 127) << 6;
    const int q = qbase + lane;                    // local query id 0..8191
    const float* __restrict__ xp = xpAll + (size_t)batch * NN * 4;
    const v2f* __restrict__ X2 = (const v2f*)xp;   // pair h -> X2[4h..4h+3]

    // per-lane query fetch from the interleaved layout (once per block)
    const int pr = q >> 1, sub0 = q & 1;
    const float Qx = xp[pr * 8 + sub0 + 0];
    const float Qy = xp[pr * 8 + sub0 + 2];
    const float Qz = xp[pr * 8 + sub0 + 4];
    const float Qw = xp[pr * 8 + sub0 + 6];
    const v2f qx = { Qx, Qx };
    const v2f qy = { Qy, Qy };
    const v2f qz = { Qz, Qz };
    const v2f qw = { Qw, Qw };
    const v2f m2 = { -2.0f, -2.0f };

    const int h0 = wv * 256;                       // pair-index base (512 cands)
    const int laneAdj = lane - 960 * 64;           // fold bin rebase into addressing

    for (int i = threadIdx.x; i < NBIN * 64; i += 1024) hist[i] = 0u;
    if (threadIdx.x < 64) { bufCnt[threadIdx.x] = 0u; dirCnt[threadIdx.x] = 0u; }
    __syncthreads();

// one set = 4 pairs = 8 candidates = 128 B = 2x s_load_dwordx16 (wave-uniform)
#define LOADSET(S, si) do { \
        const v2f* _p = X2 + 4 * (h0 + 4 * (si)); \
        _Pragma("unroll") \
        for (int _k = 0; _k < 16; ++_k) (S)[_k] = _p[_k]; } while (0)

// distance math for pair j of a set (identical op sequence in both passes
// -> identical bits -> histogram/selection consistency)
#define PAIRD2(S, j, d2) \
        v2f _dot = __builtin_elementwise_fma(qx, (S)[4*(j)+0], \
                   __builtin_elementwise_fma(qy, (S)[4*(j)+1], \
                                             qz * (S)[4*(j)+2])); \
        v2f d2   = __builtin_elementwise_fma(m2, _dot, qw + (S)[4*(j)+3]);

#define P1SET(S) do { \
        _Pragma("unroll") \
        for (int _j = 0; _j < 4; ++_j) { \
            PAIRD2(S, _j, _d2) \
            int _t0 = ((int)__float_as_uint(_d2.x)) >> 20; \
            int _t1 = ((int)__float_as_uint(_d2.y)) >> 20; \
            int _b0 = min(max(_t0, 960), 1088);            /* v_med3_i32 */ \
            int _b1 = min(max(_t1, 960), 1088); \
            atomicAdd(&hist[_b0 * 64 + laneAdj], 1u); \
            atomicAdd(&hist[_b1 * 64 + laneAdj], 1u); \
        } } while (0)

    // ---- pass 1: histogram; ping-pong prefetch (sets 0..63; prefetch of
    // set 64 overruns this wave's chunk by 128 B -> still inside the
    // workspace (next chunk / next batch / vfeat region) -> safe.
    {
        v2f A[16], Bv[16];
        LOADSET(A, 0);
        #pragma unroll 1
        for (int it = 0; it < 32; ++it) {
            LOADSET(Bv, 2 * it + 1);
            P1SET(A);
            LOADSET(A, 2 * it + 2);
            P1SET(Bv);
        }
    }
    __syncthreads();

    // ---- find crossing bin (threads 0..63, one query each) ----
    if (threadIdx.x < 64) {
        int cum = 0, Bq = 128, cl = 0;
        for (int b2 = 0; b2 < NBIN; ++b2) {
            int c = (int)hist[b2 * 64 + threadIdx.x];
            if (cum + c >= KK) { Bq = b2; cl = cum; break; }
            cum += c;
        }
        binB[threadIdx.x] = Bq;
        cumLoA[threadIdx.x] = cl;
    }
    __syncthreads();

    // ---- per-lane BITS-domain thresholds for pass 2 ----
    const int Bq = binB[lane];
    const int TLb = (Bq > 0)    ? ((960 + Bq) << 20) : INT_MIN;
    const int THb = (Bq == 128) ? INT_MAX : (((960 + Bq + 1) << 20) - 1);
    const int grow = batch * NN + q;
    const int gBase = batch * NN;

#define EMIT(Bx, jj) do { \
        if ((Bx) <= THb) {                       /* rare (~1% of candidates) */ \
            if ((Bx) < TLb) { \
                uint32_t pos = atomicAdd(&dirCnt[lane], 1u); \
                idx_ws[grow * KK + (int)pos] = gBase + (jj); \
            } else { \
                uint32_t db = (uint32_t)max((Bx), 0);        /* exact key */ \
                uint32_t pos = atomicAdd(&bufCnt[lane], 1u); \
                if (pos < 64u) buf2[lane][(int)pos] = \
                    ((unsigned long long)db << 32) | (uint32_t)(jj); \
            } \
        } } while (0)

#define P2SET(S, si) do { \
        _Pragma("unroll") \
        for (int _j = 0; _j < 4; ++_j) { \
            PAIRD2(S, _j, _d2) \
            int _B0 = (int)__float_as_uint(_d2.x); \
            int _B1 = (int)__float_as_uint(_d2.y); \
            const int _jb = 2 * (h0 + 4 * (si) + _j); \
            EMIT(_B0, _jb + 0); \
            EMIT(_B1, _jb + 1); \
        } } while (0)

    // ---- pass 2: one-compare hot path; same ping-pong pipeline ----
    {
        v2f A[16], Bv[16];
        LOADSET(A, 0);
        #pragma unroll 1
        for (int it = 0; it < 32; ++it) {
            LOADSET(Bv, 2 * it + 1);
            P2SET(A, 2 * it);
            LOADSET(A, 2 * it + 2);
            P2SET(Bv, 2 * it + 1);
        }
    }
    __syncthreads();

#undef LOADSET
#undef PAIRD2
#undef P1SET
#undef P2SET
#undef EMIT

    // ---- final: pick (36 - cumLo) smallest exact keys from boundary bin.
    // Parallel across all 16 waves: wave wv owns queries 4wv..4wv+3; keys
    // one-per-lane; each pick is a 6-step shfl_xor 64-bit min-reduce.
    // Keys are unique (low 32 bits = candidate index) -> unique argmin.
    #pragma unroll 1
    for (int sub = 0; sub < 4; ++sub) {
        const int t = 4 * wv + sub;                 // wave-uniform query slot
        const int cl = cumLoA[t];
        const int r = KK - cl;                      // >= 1 always
        const int M = min((int)bufCnt[t], 64);
        const int q2 = qbase + t;
        const int outp = (batch * NN + q2) * KK + cl;
        unsigned long long key = (lane < M) ? buf2[t][lane] : ~0ULL;
        #pragma unroll 1
        for (int i = 0; i < r; ++i) {
            unsigned long long mk = key;
            #pragma unroll
            for (int d = 32; d >= 1; d >>= 1) {
                unsigned long long o = shflx_ull(mk, d);
                mk = (o < mk) ? o : mk;
            }
            int jj = (mk == ~0ULL) ? q2 : (int)(uint32_t)(mk & 0xFFFFFFFFu);
            if (jj < 0 || jj >= NN) jj = q2;         // pathological fallback
            if (lane == 0) idx_ws[outp + i] = batch * NN + jj;
            if (key == mk) key = ~0ULL;              // retire the winner
        }
    }
}

// ---------------------------------------------------------------------------
// Kernel 3: attention + projection. One point per wave, 8192 blocks of 256.
//
// R6 change: XCD-CONTIGUOUS BLOCK SWIZZLE. Inferred k_att ~ 90-100us (total
// 242.7 - k_knn 135.4 - k_vfeat ~5): per point it gathers 36 feat rows +
// 36 vfeat rows ~ 18KB -> 600MB total. Per batch feat+vfeat = 4MB ~ one
// XCD's L2; default round-robin dispatch mixes all 4 batches onto every XCD
// (16MB through 4MiB L2 -> miss to L3). Mapping hw block (hw%8 = XCD under
// round-robin) to logical chunk (hw&7)*1024 + hw>>3 gives each XCD one
// contiguous half-batch of queries -> gather working set = that batch's
// 4MB -> L2-resident. Bijective (8192 % 8 == 0). Correctness-neutral
// permutation of block->point mapping.
// ---------------------------------------------------------------------------
#define IDX(k) ((((k) & 3) == 0 ? I[(k) >> 2].x : ((k) & 3) == 1 ? I[(k) >> 2].y : \
                 ((k) & 3) == 2 ? I[(k) >> 2].z : I[(k) >> 2].w) & (NPTS - 1))

__global__ __launch_bounds__(256) void k_att(
    const float* __restrict__ feat, const float* __restrict__ vfeat,
    const int* __restrict__ idxw, const float* __restrict__ Wsuf,
    const float* __restrict__ bsuf, float* __restrict__ out)
{
    __shared__ float G[4][KK][33];   // 19,008 B (stride 33 == 1 mod 32: <=2-way)
    const int lane = laneid();
    const int wv = waveid_uniform();
    // XCD-contiguous swizzle: 8192 blocks, 8 XCDs, 1024 blocks/XCD chunk
    const int hw = blockIdx.x;
    const int bid = (hw & 7) * (NPTS / 4 / 8) + (hw >> 3);
    const int p = bid * 4 + wv;

    // preload all 36 neighbor indices (wave-uniform s_load)
    const int4* __restrict__ myidx4 = (const int4*)(idxw + p * KK);
    int4 I[9];
    #pragma unroll
    for (int t = 0; t < 9; ++t) I[t] = myidx4[t];

    const float* __restrict__ Fp = feat + (size_t)p * CC;  // uniform -> s_load

    const int half = lane >> 5;       // 0: rows 2kk, 1: rows 2kk+1
    const int cpart = lane & 31;      // column within the 32-wide half

    float a = 0.0f;
    #pragma unroll
    for (int h = 0; h < 2; ++h) {
        // stage half h: 18 wave-loads, each covering two rows' 32-col halves
        #pragma unroll
        for (int kk = 0; kk < 18; ++kk) {
            int jrow = half ? IDX(2 * kk + 1) : IDX(2 * kk);
            G[wv][2 * kk + half][cpart] = feat[(size_t)jrow * CC + h * 32 + cpart];
        }
        // partial logits over this channel half (lane = k < 36); F is scalar
        if (lane < KK) {
            #pragma unroll 8
            for (int c = 0; c < 32; ++c)
                a = fmaf(Fp[h * 32 + c], G[wv][lane][c], a);
        }
    }
    const float logit = (lane < KK) ? a : -1e30f;

    // softmax across the 36 logit lanes — DPP (VALU pipe), no LDS
    const float m = wave_max_dpp(logit);
    const float e = (lane < KK) ? __expf(logit - m) : 0.0f;
    const float s = wave_sum_dpp(e);
    const float w = e * __frcp_rn(s);            // per-lane weight (0 for >=36)

    // weighted V gather: lane = channel; weight broadcast via v_readlane
    float acc = 0.0f;
    #pragma unroll
    for (int k = 0; k < KK; ++k) {
        float wk = rdlane_f(w, k);
        int j = IDX(k);
        acc = fmaf(wk, vfeat[j * OUTD + lane], acc);
    }

    // projection: o[lane] = b[lane] + sum_c acc_c * Wsuf[c][lane]
    float o = bsuf[lane];
    #pragma unroll 8
    for (int c = 0; c < OUTD; ++c) {
        float ac = rdlane_f(acc, c);
        o = fmaf(ac, Wsuf[c * OUTD + lane], o);
    }
    out[(size_t)p * OUTD + lane] = o;

    if (p == 0 && lane == 0) out[(size_t)NPTS * OUTD] = (float)NN;  // scalar N
}

// ---------------------------------------------------------------------------
extern "C" void kernel_launch(void* const* d_in, const int* in_sizes, int n_in,
                              void* d_out, int out_size, void* d_ws, size_t ws_size,
                              hipStream_t stream)
{
    const float* feat = (const float*)d_in[0];
    const float* xyz  = (const float*)d_in[1];
    const float* Wv   = (const float*)d_in[2];
    const float* bv   = (const float*)d_in[3];
    const float* Wsuf = (const float*)d_in[4];
    const float* bsuf = (const float*)d_in[5];
    float* out = (float*)d_out;

    char* ws = (char*)d_ws;
    float* xp = (float*)ws;                                   // 512 KB interleaved
    float*  vfeat = (float*)(ws + (512 << 10));               // 8 MB
    int*    idxw  = (int*)(ws + (512 << 10) + (8 << 20));     // 4.5 MB

    k_vfeat<<<NPTS / 32, 256, 0, stream>>>(feat, xyz, Wv, bv, vfeat, xp);
    k_knn  <<<NPTS / 64, 1024, 0, stream>>>(xp, idxw);
    k_att  <<<NPTS / 4, 256, 0, stream>>>(feat, vfeat, idxw, Wsuf, bsuf, out);
}

// Round 7
// 244.157 us; speedup vs baseline: 1.0960x; 1.0002x over previous
//
#include <hip/hip_runtime.h>
#include <stdint.h>
#include <limits.h>

// Problem constants (reference: B=4, N=8192, C=64, OUT=64, KNN=36)
#define BB 4
#define NN 8192
#define CC 64
#define OUTD 64
#define KK 36
#define NPTS (BB * NN)          // 32768
#define NBIN 129                // bins 0..128 (0 and 128 are clamp catch-alls)
// t = signed(float_bits(d2)) >> 20 (arith); bin = med3_i32(t,960,1088) - 960.
// Negative d2 (fp rounding) -> t very negative -> bin 0. One integer t per bin.
//
// xyzw layout: PAIR-INTERLEAVED. For even j: 8 floats
//   [x_j, x_j1, y_j, y_j1, z_j, z_j1, w_j, w_j1]   (j1 = j+1; 32 B per pair)
//
// Ledger (HW-validated R0-R6):
//   R0/R2  k_knn SMEM s_load + pk math     -> fast (validated 135us)
//   R1     per-lane VMEM broadcast         -> 1.9x REGRESSION
//   R3     global_load_lds + ds_read       -> REGRESSION (DS pipe shared with
//          histogram atomics) + DPP prefix-scan row_mask bug
//   R4/R5  4-buffer SGPR rotation          -> container died twice; QUARANTINED
//   R6     k_att XCD swizzle               -> NULL (resident window already
//          single-batch; k_att is not L2-capacity-bound)
// R7: k_knn/k_vfeat FROZEN (byte-identical R2). k_att rewritten per G13:
// float4 gathers (was 4 B/lane scalar!), 9-instr stage, float2 LDS logit,
// group-partitioned PV with shfl_xor reduce. ~136 -> ~82 VMEM instr/wave.

typedef float v2f __attribute__((ext_vector_type(2)));

static __device__ __forceinline__ int laneid() { return threadIdx.x & 63; }
static __device__ __forceinline__ int waveid_uniform() {
    return __builtin_amdgcn_readfirstlane((int)(threadIdx.x >> 6));
}
static __device__ __forceinline__ float rdlane_f(float v, int l) {
    return __int_as_float(__builtin_amdgcn_readlane(__float_as_int(v), l));
}
static __device__ __forceinline__ unsigned long long shflx_ull(
        unsigned long long v, int m) {
    uint32_t lo = (uint32_t)v, hi = (uint32_t)(v >> 32);
    lo = (uint32_t)__shfl_xor((int)lo, m, 64);
    hi = (uint32_t)__shfl_xor((int)hi, m, 64);
    return ((unsigned long long)hi << 32) | lo;
}
// DPP helper: VALU-pipe cross-lane (no LDS). ctrl/bound must be constants.
#define DPP_F(oldv, v, ctrl, bound) \
    __int_as_float(__builtin_amdgcn_update_dpp( \
        __float_as_int(oldv), __float_as_int(v), (ctrl), 0xf, 0xf, (bound)))

// 64-lane sum: result in lane 63 (row_shr prefix + row_bcast combine).
// NOTE: lane-63 TOTAL is correct with full row_mask; intermediate lanes are
// NOT a valid prefix (R3 lesson - do not reuse this as a scan).
static __device__ __forceinline__ float wave_sum_dpp(float v) {
    v += DPP_F(0.0f, v, 0x111, true);   // row_shr:1
    v += DPP_F(0.0f, v, 0x112, true);   // row_shr:2
    v += DPP_F(0.0f, v, 0x114, true);   // row_shr:4
    v += DPP_F(0.0f, v, 0x118, true);   // row_shr:8
    v += DPP_F(0.0f, v, 0x142, true);   // row_bcast:15
    v += DPP_F(0.0f, v, 0x143, true);   // row_bcast:31
    return rdlane_f(v, 63);
}
// 64-lane max: OOB lanes keep old=v (no-op under max)
static __device__ __forceinline__ float wave_max_dpp(float v) {
    v = fmaxf(v, DPP_F(v, v, 0x111, false));
    v = fmaxf(v, DPP_F(v, v, 0x112, false));
    v = fmaxf(v, DPP_F(v, v, 0x114, false));
    v = fmaxf(v, DPP_F(v, v, 0x118, false));
    v = fmaxf(v, DPP_F(v, v, 0x142, false));
    v = fmaxf(v, DPP_F(v, v, 0x143, false));
    return rdlane_f(v, 63);
}

// ---------------------------------------------------------------------------
// Kernel 1: v_feat = relu([feature, xyz] @ W_v + b_v)  + pair-interleaved xyzw.
// One wave handles 8 points. Block = 256 = 4 waves. grid = NPTS/32.
// ---------------------------------------------------------------------------
__global__ __launch_bounds__(256) void k_vfeat(
    const float* __restrict__ feat, const float* __restrict__ xyz,
    const float* __restrict__ Wv, const float* __restrict__ bv,
    float* __restrict__ vfeat, float* __restrict__ xp)   // xp: interleaved xyzw
{
    __shared__ float fb[4][8][64];
    __shared__ float xb[4][8][3];
    const int lane = laneid();
    const int wv = waveid_uniform();
    const int pbase = blockIdx.x * 32 + wv * 8;

    #pragma unroll
    for (int pp = 0; pp < 8; ++pp)
        fb[wv][pp][lane] = feat[(pbase + pp) * CC + lane];
    if (lane < 24)
        xb[wv][lane / 3][lane % 3] = xyz[pbase * 3 + lane];
    // same-wave LDS write->read: in-order per wave, compiler inserts lgkmcnt

    const float b0 = bv[lane];
    float acc[8];
    #pragma unroll
    for (int pp = 0; pp < 8; ++pp) acc[pp] = b0;

    #pragma unroll 4
    for (int c = 0; c < CC; ++c) {
        float w = Wv[c * OUTD + lane];
        #pragma unroll
        for (int pp = 0; pp < 8; ++pp)
            acc[pp] = fmaf(fb[wv][pp][c], w, acc[pp]);
    }
    const float wx = Wv[64 * OUTD + lane];
    const float wy = Wv[65 * OUTD + lane];
    const float wz = Wv[66 * OUTD + lane];
    #pragma unroll
    for (int pp = 0; pp < 8; ++pp) {
        float a = acc[pp];
        a = fmaf(xb[wv][pp][0], wx, a);
        a = fmaf(xb[wv][pp][1], wy, a);
        a = fmaf(xb[wv][pp][2], wz, a);
        vfeat[(pbase + pp) * OUTD + lane] = fmaxf(a, 0.0f);
    }
    if (lane < 8) {
        const int p = pbase + lane;
        const float x = xb[wv][lane][0], y = xb[wv][lane][1], z = xb[wv][lane][2];
        const float sq = (x * x + y * y) + z * z;
        const int base = (p >> 1) * 8 + (p & 1);    // pair-interleaved slot
        xp[base + 0] = x;
        xp[base + 2] = y;
        xp[base + 4] = z;
        xp[base + 6] = sq;
    }
}

// ---------------------------------------------------------------------------
// Kernel 2: 36-NN via per-query float-bit histogram selection.
// 512 blocks x 1024 thr, 64 queries/block (lane-per-query), 2 blocks/CU.
// BYTE-IDENTICAL to the R2-validated version (135us, absmax 0.0).
// ---------------------------------------------------------------------------
__global__ __launch_bounds__(1024, 8) void k_knn(
    const float* __restrict__ xpAll, int* __restrict__ idx_ws)
{
    __shared__ __align__(16) uint32_t hist[NBIN * 64];          // 33.0 KB
    __shared__ __align__(16) unsigned long long buf2[64][65];   // 33.3 KB
    __shared__ int binB[64];
    __shared__ int cumLoA[64];
    __shared__ uint32_t bufCnt[64];
    __shared__ uint32_t dirCnt[64];

    const int lane = laneid();
    const int wv = waveid_uniform();               // 0..15
    const int batch = blockIdx.x >> 7;             // 128 blocks per batch
    const int qbase = (blockIdx.x & 127) << 6;
    const int q = qbase + lane;                    // local query id 0..8191
    const float* __restrict__ xp = xpAll + (size_t)batch * NN * 4;
    const v2f* __restrict__ X2 = (const v2f*)xp;   // pair h -> X2[4h..4h+3]

    // per-lane query fetch from the interleaved layout (once per block)
    const int pr = q >> 1, sub0 = q & 1;
    const float Qx = xp[pr * 8 + sub0 + 0];
    const float Qy = xp[pr * 8 + sub0 + 2];
    const float Qz = xp[pr * 8 + sub0 + 4];
    const float Qw = xp[pr * 8 + sub0 + 6];
    const v2f qx = { Qx, Qx };
    const v2f qy = { Qy, Qy };
    const v2f qz = { Qz, Qz };
    const v2f qw = { Qw, Qw };
    const v2f m2 = { -2.0f, -2.0f };

    const int h0 = wv * 256;                       // pair-index base (512 cands)
    const int laneAdj = lane - 960 * 64;           // fold bin rebase into addressing

    for (int i = threadIdx.x; i < NBIN * 64; i += 1024) hist[i] = 0u;
    if (threadIdx.x < 64) { bufCnt[threadIdx.x] = 0u; dirCnt[threadIdx.x] = 0u; }
    __syncthreads();

// one set = 4 pairs = 8 candidates = 128 B = 2x s_load_dwordx16 (wave-uniform)
#define LOADSET(S, si) do { \
        const v2f* _p = X2 + 4 * (h0 + 4 * (si)); \
        _Pragma("unroll") \
        for (int _k = 0; _k < 16; ++_k) (S)[_k] = _p[_k]; } while (0)

// distance math for pair j of a set (identical op sequence in both passes
// -> identical bits -> histogram/selection consistency)
#define PAIRD2(S, j, d2) \
        v2f _dot = __builtin_elementwise_fma(qx, (S)[4*(j)+0], \
                   __builtin_elementwise_fma(qy, (S)[4*(j)+1], \
                                             qz * (S)[4*(j)+2])); \
        v2f d2   = __builtin_elementwise_fma(m2, _dot, qw + (S)[4*(j)+3]);

#define P1SET(S) do { \
        _Pragma("unroll") \
        for (int _j = 0; _j < 4; ++_j) { \
            PAIRD2(S, _j, _d2) \
            int _t0 = ((int)__float_as_uint(_d2.x)) >> 20; \
            int _t1 = ((int)__float_as_uint(_d2.y)) >> 20; \
            int _b0 = min(max(_t0, 960), 1088);            /* v_med3_i32 */ \
            int _b1 = min(max(_t1, 960), 1088); \
            atomicAdd(&hist[_b0 * 64 + laneAdj], 1u); \
            atomicAdd(&hist[_b1 * 64 + laneAdj], 1u); \
        } } while (0)

    // ---- pass 1: histogram; ping-pong prefetch (sets 0..63; prefetch of
    // set 64 overruns this wave's chunk by 128 B -> still inside the
    // workspace (next chunk / next batch / vfeat region) -> safe.
    {
        v2f A[16], Bv[16];
        LOADSET(A, 0);
        #pragma unroll 1
        for (int it = 0; it < 32; ++it) {
            LOADSET(Bv, 2 * it + 1);
            P1SET(A);
            LOADSET(A, 2 * it + 2);
            P1SET(Bv);
        }
    }
    __syncthreads();

    // ---- find crossing bin (threads 0..63, one query each) ----
    if (threadIdx.x < 64) {
        int cum = 0, Bq = 128, cl = 0;
        for (int b2 = 0; b2 < NBIN; ++b2) {
            int c = (int)hist[b2 * 64 + threadIdx.x];
            if (cum + c >= KK) { Bq = b2; cl = cum; break; }
            cum += c;
        }
        binB[threadIdx.x] = Bq;
        cumLoA[threadIdx.x] = cl;
    }
    __syncthreads();

    // ---- per-lane BITS-domain thresholds for pass 2 ----
    const int Bq = binB[lane];
    const int TLb = (Bq > 0)    ? ((960 + Bq) << 20) : INT_MIN;
    const int THb = (Bq == 128) ? INT_MAX : (((960 + Bq + 1) << 20) - 1);
    const int grow = batch * NN + q;
    const int gBase = batch * NN;

#define EMIT(Bx, jj) do { \
        if ((Bx) <= THb) {                       /* rare (~1% of candidates) */ \
            if ((Bx) < TLb) { \
                uint32_t pos = atomicAdd(&dirCnt[lane], 1u); \
                idx_ws[grow * KK + (int)pos] = gBase + (jj); \
            } else { \
                uint32_t db = (uint32_t)max((Bx), 0);        /* exact key */ \
                uint32_t pos = atomicAdd(&bufCnt[lane], 1u); \
                if (pos < 64u) buf2[lane][(int)pos] = \
                    ((unsigned long long)db << 32) | (uint32_t)(jj); \
            } \
        } } while (0)

#define P2SET(S, si) do { \
        _Pragma("unroll") \
        for (int _j = 0; _j < 4; ++_j) { \
            PAIRD2(S, _j, _d2) \
            int _B0 = (int)__float_as_uint(_d2.x); \
            int _B1 = (int)__float_as_uint(_d2.y); \
            const int _jb = 2 * (h0 + 4 * (si) + _j); \
            EMIT(_B0, _jb + 0); \
            EMIT(_B1, _jb + 1); \
        } } while (0)

    // ---- pass 2: one-compare hot path; same ping-pong pipeline ----
    {
        v2f A[16], Bv[16];
        LOADSET(A, 0);
        #pragma unroll 1
        for (int it = 0; it < 32; ++it) {
            LOADSET(Bv, 2 * it + 1);
            P2SET(A, 2 * it);
            LOADSET(A, 2 * it + 2);
            P2SET(Bv, 2 * it + 1);
        }
    }
    __syncthreads();

#undef LOADSET
#undef PAIRD2
#undef P1SET
#undef P2SET
#undef EMIT

    // ---- final: pick (36 - cumLo) smallest exact keys from boundary bin.
    // Parallel across all 16 waves: wave wv owns queries 4wv..4wv+3; keys
    // one-per-lane; each pick is a 6-step shfl_xor 64-bit min-reduce.
    // Keys are unique (low 32 bits = candidate index) -> unique argmin.
    #pragma unroll 1
    for (int sub = 0; sub < 4; ++sub) {
        const int t = 4 * wv + sub;                 // wave-uniform query slot
        const int cl = cumLoA[t];
        const int r = KK - cl;                      // >= 1 always
        const int M = min((int)bufCnt[t], 64);
        const int q2 = qbase + t;
        const int outp = (batch * NN + q2) * KK + cl;
        unsigned long long key = (lane < M) ? buf2[t][lane] : ~0ULL;
        #pragma unroll 1
        for (int i = 0; i < r; ++i) {
            unsigned long long mk = key;
            #pragma unroll
            for (int d = 32; d >= 1; d >>= 1) {
                unsigned long long o = shflx_ull(mk, d);
                mk = (o < mk) ? o : mk;
            }
            int jj = (mk == ~0ULL) ? q2 : (int)(uint32_t)(mk & 0xFFFFFFFFu);
            if (jj < 0 || jj >= NN) jj = q2;         // pathological fallback
            if (lane == 0) idx_ws[outp + i] = batch * NN + jj;
            if (key == mk) key = ~0ULL;              // retire the winner
        }
    }
}

// ---------------------------------------------------------------------------
// Kernel 3 (R7 rewrite): attention + projection with FLOAT4 gathers.
// One point per wave, 8192 blocks of 256 (4 waves).
// Lane layout: g = lane>>4 (neighbor subgroup 0..3), qd = lane&15 (chan quad).
// jsel[t] = neighbor index for k = 4t+g (t = 0..8; 9*4 = 36 neighbors).
//  - stage:  9 float4 gathers (4 rows x 16 quads = 1 KB/instr, was 36 scalar)
//            -> G[36][GS=34] via 2 aligned float2 LDS writes
//  - logit:  per-lane row (lane<36), float2 LDS reads, SAME fma order as the
//            validated version -> bit-identical logits/softmax/weights
//  - PV:     9 float4 vfeat gathers; partials over k==g (mod 4), weight via
//            __shfl(w, 4t+g); shfl_xor(16,32) combine (reassociated sum of a
//            convex combination - well within tolerance, cf. R3 passed@0.32)
//  - proj:   same order; acc quad read via readlane(component, c2)
// ---------------------------------------------------------------------------
#define GS 34   // float stride per G row: 136 B, 8-aligned for float2 ops

__global__ __launch_bounds__(256, 6) void k_att(
    const float* __restrict__ feat, const float* __restrict__ vfeat,
    const int* __restrict__ idxw, const float* __restrict__ Wsuf,
    const float* __restrict__ bsuf, float* __restrict__ out)
{
    __shared__ float G[4][KK * GS];   // 4,896 B/wave -> 19,584 B/block
    const int lane = laneid();
    const int wv = waveid_uniform();
    const int p = blockIdx.x * 4 + wv;
    const int g = lane >> 4;          // neighbor subgroup
    const int qd = lane & 15;         // channel quad

    // preload all 36 neighbor indices (wave-uniform s_load -> SGPRs)
    const int4* __restrict__ myidx4 = (const int4*)(idxw + p * KK);
    int4 I[9];
    #pragma unroll
    for (int t = 0; t < 9; ++t) I[t] = myidx4[t];

    // per-lane neighbor row for k = 4t+g (component g of I[t])
    int jsel[9];
    #pragma unroll
    for (int t = 0; t < 9; ++t) {
        const int4 v = I[t];
        int j = (g == 0) ? v.x : (g == 1) ? v.y : (g == 2) ? v.z : v.w;
        jsel[t] = j & (NPTS - 1);
    }

    // ---- stage: 9 x float4 feat gathers -> G (aligned float2 writes) ----
    #pragma unroll
    for (int t = 0; t < 9; ++t) {
        const float4 rv = *(const float4*)&feat[(size_t)jsel[t] * CC + 4 * qd];
        float* dst = &G[wv][(4 * t + g) * GS + 4 * qd];
        float2 lo, hi;
        lo.x = rv.x; lo.y = rv.y;
        hi.x = rv.z; hi.y = rv.w;
        ((float2*)dst)[0] = lo;
        ((float2*)dst)[1] = hi;
    }
    // same-wave DS ordering: writes precede reads in program order; the
    // compiler's lgkm accounting orders them (G aliasing is explicit).

    const float* __restrict__ Fp = feat + (size_t)p * CC;  // uniform -> s_load

    // ---- logit: row = lane (<36), fma order IDENTICAL to validated form ----
    float a = 0.0f;
    if (lane < KK) {
        const float* Grow = &G[wv][lane * GS];
        #pragma unroll 8
        for (int c2 = 0; c2 < 32; ++c2) {
            const float2 gv = *(const float2*)&Grow[2 * c2];
            a = fmaf(Fp[2 * c2],     gv.x, a);
            a = fmaf(Fp[2 * c2 + 1], gv.y, a);
        }
    }
    const float logit = (lane < KK) ? a : -1e30f;

    // softmax across the 36 logit lanes — DPP (VALU pipe), no LDS
    const float m = wave_max_dpp(logit);
    const float e = (lane < KK) ? __expf(logit - m) : 0.0f;
    const float s = wave_sum_dpp(e);
    const float w = e * __frcp_rn(s);            // per-lane weight (0 for >=36)

    // ---- PV: 9 x float4 vfeat gathers; partials over k == g (mod 4) ----
    float a0 = 0.0f, a1 = 0.0f, a2 = 0.0f, a3 = 0.0f;
    #pragma unroll
    for (int t = 0; t < 9; ++t) {
        const float wk = __shfl(w, 4 * t + g, 64);   // weight of neighbor 4t+g
        const float4 vv = *(const float4*)&vfeat[(size_t)jsel[t] * OUTD + 4 * qd];
        a0 = fmaf(wk, vv.x, a0);
        a1 = fmaf(wk, vv.y, a1);
        a2 = fmaf(wk, vv.z, a2);
        a3 = fmaf(wk, vv.w, a3);
    }
    // combine the 4 neighbor subgroups (lanes differing in bits 4,5)
    a0 += __shfl_xor(a0, 16, 64); a0 += __shfl_xor(a0, 32, 64);
    a1 += __shfl_xor(a1, 16, 64); a1 += __shfl_xor(a1, 32, 64);
    a2 += __shfl_xor(a2, 16, 64); a2 += __shfl_xor(a2, 32, 64);
    a3 += __shfl_xor(a3, 16, 64); a3 += __shfl_xor(a3, 32, 64);
    // now every lane with qd = c2 holds channels 4c2..4c2+3 in a0..a3

    // ---- projection: o[lane] = b[lane] + sum_c acc_c * Wsuf[c][lane] ----
    float o = bsuf[lane];
    #pragma unroll 4
    for (int c2 = 0; c2 < 16; ++c2) {
        o = fmaf(rdlane_f(a0, c2), Wsuf[(4 * c2 + 0) * OUTD + lane], o);
        o = fmaf(rdlane_f(a1, c2), Wsuf[(4 * c2 + 1) * OUTD + lane], o);
        o = fmaf(rdlane_f(a2, c2), Wsuf[(4 * c2 + 2) * OUTD + lane], o);
        o = fmaf(rdlane_f(a3, c2), Wsuf[(4 * c2 + 3) * OUTD + lane], o);
    }
    out[(size_t)p * OUTD + lane] = o;

    if (p == 0 && lane == 0) out[(size_t)NPTS * OUTD] = (float)NN;  // scalar N
}

// ---------------------------------------------------------------------------
extern "C" void kernel_launch(void* const* d_in, const int* in_sizes, int n_in,
                              void* d_out, int out_size, void* d_ws, size_t ws_size,
                              hipStream_t stream)
{
    const float* feat = (const float*)d_in[0];
    const float* xyz  = (const float*)d_in[1];
    const float* Wv   = (const float*)d_in[2];
    const float* bv   = (const float*)d_in[3];
    const float* Wsuf = (const float*)d_in[4];
    const float* bsuf = (const float*)d_in[5];
    float* out = (float*)d_out;

    char* ws = (char*)d_ws;
    float* xp = (float*)ws;                                   // 512 KB interleaved
    float*  vfeat = (float*)(ws + (512 << 10));               // 8 MB
    int*    idxw  = (int*)(ws + (512 << 10) + (8 << 20));     // 4.5 MB

    k_vfeat<<<NPTS / 32, 256, 0, stream>>>(feat, xyz, Wv, bv, vfeat, xp);
    k_knn  <<<NPTS / 64, 1024, 0, stream>>>(xp, idxw);
    k_att  <<<NPTS / 4, 256, 0, stream>>>(feat, vfeat, idxw, Wsuf, bsuf, out);
}

// Round 8
// 242.924 us; speedup vs baseline: 1.1016x; 1.0051x over previous
//
#include <hip/hip_runtime.h>
#include <stdint.h>
#include <limits.h>

// Problem constants (reference: B=4, N=8192, C=64, OUT=64, KNN=36)
#define BB 4
#define NN 8192
#define CC 64
#define OUTD 64
#define KK 36
#define NPTS (BB * NN)          // 32768
#define NBIN 129                // bins 0..128 (0 and 128 are clamp catch-alls)
// t = signed(float_bits(d2)) >> 20 (arith); bin = med3_i32(t,960,1088) - 960.
// Negative d2 (fp rounding) -> t very negative -> bin 0. One integer t per bin.
//
// xyzw layout: PAIR-INTERLEAVED. For even j: 8 floats
//   [x_j, x_j1, y_j, y_j1, z_j, z_j1, w_j, w_j1]   (j1 = j+1; 32 B per pair)
//
// Ledger (HW-validated R0-R7):
//   R0/R2  k_knn SMEM s_load + pk math     -> fast (validated 135-137us)
//   R1     per-lane VMEM broadcast         -> 1.9x REGRESSION
//   R3     global_load_lds + ds_read       -> REGRESSION (DS pipe shared with
//          histogram atomics) + DPP prefix-scan row_mask bug
//   R4/R5  4-buffer SGPR rotation          -> container died twice; QUARANTINED
//   R6     k_att XCD swizzle               -> NULL (not an L2-assignment issue)
//   R7     k_att float4 gathers            -> NULL on time (k_att is memory-
//          side bound, NOT issue-bound; gathers were already segment-
//          coalesced) AND absmax 0.59 (unlocated bug) -> QUARANTINED.
// R8: k_att = R2 scalar form (absmax 0.0 x3) + NONTEMPORAL out stores.
// Theory: k_att's ~102us == 600MB gathers at ~5.9 TB/s ~= HBM ceiling; the
// 4MB/batch gather set exactly fills one XCD L2 and the write-allocate
// streaming of `out` (2MB/batch) evicts it -> thrash. nt stores remove the
// churn; gathers should become L2-resident.

typedef float v2f __attribute__((ext_vector_type(2)));

static __device__ __forceinline__ int laneid() { return threadIdx.x & 63; }
static __device__ __forceinline__ int waveid_uniform() {
    return __builtin_amdgcn_readfirstlane((int)(threadIdx.x >> 6));
}
static __device__ __forceinline__ float rdlane_f(float v, int l) {
    return __int_as_float(__builtin_amdgcn_readlane(__float_as_int(v), l));
}
static __device__ __forceinline__ unsigned long long shflx_ull(
        unsigned long long v, int m) {
    uint32_t lo = (uint32_t)v, hi = (uint32_t)(v >> 32);
    lo = (uint32_t)__shfl_xor((int)lo, m, 64);
    hi = (uint32_t)__shfl_xor((int)hi, m, 64);
    return ((unsigned long long)hi << 32) | lo;
}
// DPP helper: VALU-pipe cross-lane (no LDS). ctrl/bound must be constants.
#define DPP_F(oldv, v, ctrl, bound) \
    __int_as_float(__builtin_amdgcn_update_dpp( \
        __float_as_int(oldv), __float_as_int(v), (ctrl), 0xf, 0xf, (bound)))

// 64-lane sum: result in lane 63 (row_shr prefix + row_bcast combine).
// NOTE: lane-63 TOTAL is correct with full row_mask; intermediate lanes are
// NOT a valid prefix (R3 lesson - do not reuse this as a scan).
static __device__ __forceinline__ float wave_sum_dpp(float v) {
    v += DPP_F(0.0f, v, 0x111, true);   // row_shr:1
    v += DPP_F(0.0f, v, 0x112, true);   // row_shr:2
    v += DPP_F(0.0f, v, 0x114, true);   // row_shr:4
    v += DPP_F(0.0f, v, 0x118, true);   // row_shr:8
    v += DPP_F(0.0f, v, 0x142, true);   // row_bcast:15
    v += DPP_F(0.0f, v, 0x143, true);   // row_bcast:31
    return rdlane_f(v, 63);
}
// 64-lane max: OOB lanes keep old=v (no-op under max)
static __device__ __forceinline__ float wave_max_dpp(float v) {
    v = fmaxf(v, DPP_F(v, v, 0x111, false));
    v = fmaxf(v, DPP_F(v, v, 0x112, false));
    v = fmaxf(v, DPP_F(v, v, 0x114, false));
    v = fmaxf(v, DPP_F(v, v, 0x118, false));
    v = fmaxf(v, DPP_F(v, v, 0x142, false));
    v = fmaxf(v, DPP_F(v, v, 0x143, false));
    return rdlane_f(v, 63);
}

// ---------------------------------------------------------------------------
// Kernel 1: v_feat = relu([feature, xyz] @ W_v + b_v)  + pair-interleaved xyzw.
// One wave handles 8 points. Block = 256 = 4 waves. grid = NPTS/32.
// ---------------------------------------------------------------------------
__global__ __launch_bounds__(256) void k_vfeat(
    const float* __restrict__ feat, const float* __restrict__ xyz,
    const float* __restrict__ Wv, const float* __restrict__ bv,
    float* __restrict__ vfeat, float* __restrict__ xp)   // xp: interleaved xyzw
{
    __shared__ float fb[4][8][64];
    __shared__ float xb[4][8][3];
    const int lane = laneid();
    const int wv = waveid_uniform();
    const int pbase = blockIdx.x * 32 + wv * 8;

    #pragma unroll
    for (int pp = 0; pp < 8; ++pp)
        fb[wv][pp][lane] = feat[(pbase + pp) * CC + lane];
    if (lane < 24)
        xb[wv][lane / 3][lane % 3] = xyz[pbase * 3 + lane];
    // same-wave LDS write->read: in-order per wave, compiler inserts lgkmcnt

    const float b0 = bv[lane];
    float acc[8];
    #pragma unroll
    for (int pp = 0; pp < 8; ++pp) acc[pp] = b0;

    #pragma unroll 4
    for (int c = 0; c < CC; ++c) {
        float w = Wv[c * OUTD + lane];
        #pragma unroll
        for (int pp = 0; pp < 8; ++pp)
            acc[pp] = fmaf(fb[wv][pp][c], w, acc[pp]);
    }
    const float wx = Wv[64 * OUTD + lane];
    const float wy = Wv[65 * OUTD + lane];
    const float wz = Wv[66 * OUTD + lane];
    #pragma unroll
    for (int pp = 0; pp < 8; ++pp) {
        float a = acc[pp];
        a = fmaf(xb[wv][pp][0], wx, a);
        a = fmaf(xb[wv][pp][1], wy, a);
        a = fmaf(xb[wv][pp][2], wz, a);
        vfeat[(pbase + pp) * OUTD + lane] = fmaxf(a, 0.0f);
    }
    if (lane < 8) {
        const int p = pbase + lane;
        const float x = xb[wv][lane][0], y = xb[wv][lane][1], z = xb[wv][lane][2];
        const float sq = (x * x + y * y) + z * z;
        const int base = (p >> 1) * 8 + (p & 1);    // pair-interleaved slot
        xp[base + 0] = x;
        xp[base + 2] = y;
        xp[base + 4] = z;
        xp[base + 6] = sq;
    }
}

// ---------------------------------------------------------------------------
// Kernel 2: 36-NN via per-query float-bit histogram selection.
// 512 blocks x 1024 thr, 64 queries/block (lane-per-query), 2 blocks/CU.
// BYTE-IDENTICAL to the R2-validated version (135us, absmax 0.0).
// ---------------------------------------------------------------------------
__global__ __launch_bounds__(1024, 8) void k_knn(
    const float* __restrict__ xpAll, int* __restrict__ idx_ws)
{
    __shared__ __align__(16) uint32_t hist[NBIN * 64];          // 33.0 KB
    __shared__ __align__(16) unsigned long long buf2[64][65];   // 33.3 KB
    __shared__ int binB[64];
    __shared__ int cumLoA[64];
    __shared__ uint32_t bufCnt[64];
    __shared__ uint32_t dirCnt[64];

    const int lane = laneid();
    const int wv = waveid_uniform();               // 0..15
    const int batch = blockIdx.x >> 7;             // 128 blocks per batch
    const int qbase = (blockIdx.x & 127) << 6;
    const int q = qbase + lane;                    // local query id 0..8191
    const float* __restrict__ xp = xpAll + (size_t)batch * NN * 4;
    const v2f* __restrict__ X2 = (const v2f*)xp;   // pair h -> X2[4h..4h+3]

    // per-lane query fetch from the interleaved layout (once per block)
    const int pr = q >> 1, sub0 = q & 1;
    const float Qx = xp[pr * 8 + sub0 + 0];
    const float Qy = xp[pr * 8 + sub0 + 2];
    const float Qz = xp[pr * 8 + sub0 + 4];
    const float Qw = xp[pr * 8 + sub0 + 6];
    const v2f qx = { Qx, Qx };
    const v2f qy = { Qy, Qy };
    const v2f qz = { Qz, Qz };
    const v2f qw = { Qw, Qw };
    const v2f m2 = { -2.0f, -2.0f };

    const int h0 = wv * 256;                       // pair-index base (512 cands)
    const int laneAdj = lane - 960 * 64;           // fold bin rebase into addressing

    for (int i = threadIdx.x; i < NBIN * 64; i += 1024) hist[i] = 0u;
    if (threadIdx.x < 64) { bufCnt[threadIdx.x] = 0u; dirCnt[threadIdx.x] = 0u; }
    __syncthreads();

// one set = 4 pairs = 8 candidates = 128 B = 2x s_load_dwordx16 (wave-uniform)
#define LOADSET(S, si) do { \
        const v2f* _p = X2 + 4 * (h0 + 4 * (si)); \
        _Pragma("unroll") \
        for (int _k = 0; _k < 16; ++_k) (S)[_k] = _p[_k]; } while (0)

// distance math for pair j of a set (identical op sequence in both passes
// -> identical bits -> histogram/selection consistency)
#define PAIRD2(S, j, d2) \
        v2f _dot = __builtin_elementwise_fma(qx, (S)[4*(j)+0], \
                   __builtin_elementwise_fma(qy, (S)[4*(j)+1], \
                                             qz * (S)[4*(j)+2])); \
        v2f d2   = __builtin_elementwise_fma(m2, _dot, qw + (S)[4*(j)+3]);

#define P1SET(S) do { \
        _Pragma("unroll") \
        for (int _j = 0; _j < 4; ++_j) { \
            PAIRD2(S, _j, _d2) \
            int _t0 = ((int)__float_as_uint(_d2.x)) >> 20; \
            int _t1 = ((int)__float_as_uint(_d2.y)) >> 20; \
            int _b0 = min(max(_t0, 960), 1088);            /* v_med3_i32 */ \
            int _b1 = min(max(_t1, 960), 1088); \
            atomicAdd(&hist[_b0 * 64 + laneAdj], 1u); \
            atomicAdd(&hist[_b1 * 64 + laneAdj], 1u); \
        } } while (0)

    // ---- pass 1: histogram; ping-pong prefetch (sets 0..63; prefetch of
    // set 64 overruns this wave's chunk by 128 B -> still inside the
    // workspace (next chunk / next batch / vfeat region) -> safe.
    {
        v2f A[16], Bv[16];
        LOADSET(A, 0);
        #pragma unroll 1
        for (int it = 0; it < 32; ++it) {
            LOADSET(Bv, 2 * it + 1);
            P1SET(A);
            LOADSET(A, 2 * it + 2);
            P1SET(Bv);
        }
    }
    __syncthreads();

    // ---- find crossing bin (threads 0..63, one query each) ----
    if (threadIdx.x < 64) {
        int cum = 0, Bq = 128, cl = 0;
        for (int b2 = 0; b2 < NBIN; ++b2) {
            int c = (int)hist[b2 * 64 + threadIdx.x];
            if (cum + c >= KK) { Bq = b2; cl = cum; break; }
            cum += c;
        }
        binB[threadIdx.x] = Bq;
        cumLoA[threadIdx.x] = cl;
    }
    __syncthreads();

    // ---- per-lane BITS-domain thresholds for pass 2 ----
    const int Bq = binB[lane];
    const int TLb = (Bq > 0)    ? ((960 + Bq) << 20) : INT_MIN;
    const int THb = (Bq == 128) ? INT_MAX : (((960 + Bq + 1) << 20) - 1);
    const int grow = batch * NN + q;
    const int gBase = batch * NN;

#define EMIT(Bx, jj) do { \
        if ((Bx) <= THb) {                       /* rare (~1% of candidates) */ \
            if ((Bx) < TLb) { \
                uint32_t pos = atomicAdd(&dirCnt[lane], 1u); \
                idx_ws[grow * KK + (int)pos] = gBase + (jj); \
            } else { \
                uint32_t db = (uint32_t)max((Bx), 0);        /* exact key */ \
                uint32_t pos = atomicAdd(&bufCnt[lane], 1u); \
                if (pos < 64u) buf2[lane][(int)pos] = \
                    ((unsigned long long)db << 32) | (uint32_t)(jj); \
            } \
        } } while (0)

#define P2SET(S, si) do { \
        _Pragma("unroll") \
        for (int _j = 0; _j < 4; ++_j) { \
            PAIRD2(S, _j, _d2) \
            int _B0 = (int)__float_as_uint(_d2.x); \
            int _B1 = (int)__float_as_uint(_d2.y); \
            const int _jb = 2 * (h0 + 4 * (si) + _j); \
            EMIT(_B0, _jb + 0); \
            EMIT(_B1, _jb + 1); \
        } } while (0)

    // ---- pass 2: one-compare hot path; same ping-pong pipeline ----
    {
        v2f A[16], Bv[16];
        LOADSET(A, 0);
        #pragma unroll 1
        for (int it = 0; it < 32; ++it) {
            LOADSET(Bv, 2 * it + 1);
            P2SET(A, 2 * it);
            LOADSET(A, 2 * it + 2);
            P2SET(Bv, 2 * it + 1);
        }
    }
    __syncthreads();

#undef LOADSET
#undef PAIRD2
#undef P1SET
#undef P2SET
#undef EMIT

    // ---- final: pick (36 - cumLo) smallest exact keys from boundary bin.
    // Parallel across all 16 waves: wave wv owns queries 4wv..4wv+3; keys
    // one-per-lane; each pick is a 6-step shfl_xor 64-bit min-reduce.
    // Keys are unique (low 32 bits = candidate index) -> unique argmin.
    #pragma unroll 1
    for (int sub = 0; sub < 4; ++sub) {
        const int t = 4 * wv + sub;                 // wave-uniform query slot
        const int cl = cumLoA[t];
        const int r = KK - cl;                      // >= 1 always
        const int M = min((int)bufCnt[t], 64);
        const int q2 = qbase + t;
        const int outp = (batch * NN + q2) * KK + cl;
        unsigned long long key = (lane < M) ? buf2[t][lane] : ~0ULL;
        #pragma unroll 1
        for (int i = 0; i < r; ++i) {
            unsigned long long mk = key;
            #pragma unroll
            for (int d = 32; d >= 1; d >>= 1) {
                unsigned long long o = shflx_ull(mk, d);
                mk = (o < mk) ? o : mk;
            }
            int jj = (mk == ~0ULL) ? q2 : (int)(uint32_t)(mk & 0xFFFFFFFFu);
            if (jj < 0 || jj >= NN) jj = q2;         // pathological fallback
            if (lane == 0) idx_ws[outp + i] = batch * NN + jj;
            if (key == mk) key = ~0ULL;              // retire the winner
        }
    }
}

// ---------------------------------------------------------------------------
// Kernel 3: attention + projection — R2-validated scalar form (absmax 0.0 x3)
// with ONE change: `out` stores are NONTEMPORAL (no L2 allocation).
// Rationale (R8 theory): k_att's gathers need the 4MB/batch feat+vfeat set
// resident in each XCD's 4MB L2; streaming write-allocate of `out`
// (2MB/batch) evicts it -> gathers fall to HBM (~5.9 TB/s effective
// matches the measured 102us). nt stores remove the churn.
// grid = NPTS/4 blocks of 256, one point per wave. No __syncthreads.
// ---------------------------------------------------------------------------
#define IDX(k) ((((k) & 3) == 0 ? I[(k) >> 2].x : ((k) & 3) == 1 ? I[(k) >> 2].y : \
                 ((k) & 3) == 2 ? I[(k) >> 2].z : I[(k) >> 2].w) & (NPTS - 1))

__global__ __launch_bounds__(256) void k_att(
    const float* __restrict__ feat, const float* __restrict__ vfeat,
    const int* __restrict__ idxw, const float* __restrict__ Wsuf,
    const float* __restrict__ bsuf, float* __restrict__ out)
{
    __shared__ float G[4][KK][33];   // 19,008 B (stride 33 == 1 mod 32: <=2-way)
    const int lane = laneid();
    const int wv = waveid_uniform();
    const int p = blockIdx.x * 4 + wv;

    // preload all 36 neighbor indices (wave-uniform s_load)
    const int4* __restrict__ myidx4 = (const int4*)(idxw + p * KK);
    int4 I[9];
    #pragma unroll
    for (int t = 0; t < 9; ++t) I[t] = myidx4[t];

    const float* __restrict__ Fp = feat + (size_t)p * CC;  // uniform -> s_load

    const int half = lane >> 5;       // 0: rows 2kk, 1: rows 2kk+1
    const int cpart = lane & 31;      // column within the 32-wide half

    float a = 0.0f;
    #pragma unroll
    for (int h = 0; h < 2; ++h) {
        // stage half h: 18 wave-loads, each covering two rows' 32-col halves
        #pragma unroll
        for (int kk = 0; kk < 18; ++kk) {
            int jrow = half ? IDX(2 * kk + 1) : IDX(2 * kk);
            G[wv][2 * kk + half][cpart] = feat[(size_t)jrow * CC + h * 32 + cpart];
        }
        // partial logits over this channel half (lane = k < 36); F is scalar
        if (lane < KK) {
            #pragma unroll 8
            for (int c = 0; c < 32; ++c)
                a = fmaf(Fp[h * 32 + c], G[wv][lane][c], a);
        }
    }
    const float logit = (lane < KK) ? a : -1e30f;

    // softmax across the 36 logit lanes — DPP (VALU pipe), no LDS
    const float m = wave_max_dpp(logit);
    const float e = (lane < KK) ? __expf(logit - m) : 0.0f;
    const float s = wave_sum_dpp(e);
    const float w = e * __frcp_rn(s);            // per-lane weight (0 for >=36)

    // weighted V gather: lane = channel; weight broadcast via v_readlane
    float acc = 0.0f;
    #pragma unroll
    for (int k = 0; k < KK; ++k) {
        float wk = rdlane_f(w, k);
        int j = IDX(k);
        acc = fmaf(wk, vfeat[j * OUTD + lane], acc);
    }

    // projection: o[lane] = b[lane] + sum_c acc_c * Wsuf[c][lane]
    float o = bsuf[lane];
    #pragma unroll 8
    for (int c = 0; c < OUTD; ++c) {
        float ac = rdlane_f(acc, c);
        o = fmaf(ac, Wsuf[c * OUTD + lane], o);
    }
    // NONTEMPORAL store: do not allocate `out` lines in L2 (R8 experiment)
    __builtin_nontemporal_store(o, &out[(size_t)p * OUTD + lane]);

    if (p == 0 && lane == 0) out[(size_t)NPTS * OUTD] = (float)NN;  // scalar N
}

// ---------------------------------------------------------------------------
extern "C" void kernel_launch(void* const* d_in, const int* in_sizes, int n_in,
                              void* d_out, int out_size, void* d_ws, size_t ws_size,
                              hipStream_t stream)
{
    const float* feat = (const float*)d_in[0];
    const float* xyz  = (const float*)d_in[1];
    const float* Wv   = (const float*)d_in[2];
    const float* bv   = (const float*)d_in[3];
    const float* Wsuf = (const float*)d_in[4];
    const float* bsuf = (const float*)d_in[5];
    float* out = (float*)d_out;

    char* ws = (char*)d_ws;
    float* xp = (float*)ws;                                   // 512 KB interleaved
    float*  vfeat = (float*)(ws + (512 << 10));               // 8 MB
    int*    idxw  = (int*)(ws + (512 << 10) + (8 << 20));     // 4.5 MB

    k_vfeat<<<NPTS / 32, 256, 0, stream>>>(feat, xyz, Wv, bv, vfeat, xp);
    k_knn  <<<NPTS / 64, 1024, 0, stream>>>(xp, idxw);
    k_att  <<<NPTS / 4, 256, 0, stream>>>(feat, vfeat, idxw, Wsuf, bsuf, out);
}